// Round 4
// baseline (14431.947 us; speedup 1.0000x reference)
//
#include <hip/hip_runtime.h>
#include <math.h>

// VanillaRNN, bit-exact chain semantics (R9 ordering preserved exactly):
//   * per-row z[i] = ascending-k single FMA chain k=0..255, init 0, split
//     P: k=0..127 -> exact float LDS handoff -> Q: k=128..255.
//   * z = ((W_hx*x_t) + chain) + bias_h, separately rounded, left-assoc
//   * tanh = Eigen/XLA fast-tanh WITH FMA (clamp 7.99881172180175781f)
//
// R12 — why (counter evidence across R9/R10/R11):
//   * R9 wall = 3600 cyc/u-iter ~= 512 broadcast ds_read_b128 x ~7cyc:
//     LDS pipe ~97% busy => LDS-INSTRUCTION-COUNT bound. R8->R9 proved
//     ~1100 cyc/step of VALU slack exists (removing it left wall flat).
//   * Broadcast instr count = FMA_work/(64 lanes*4) — schedule-invariant.
//     Only MORE ROWS PER THREAD raises FMAs-per-broadcast (quad feeds 2
//     chains = 8 FMAs). So: 256 threads (4 waves), thread owns rows
//     {i, i+128} for its k-half. LDS instrs/u: 512 -> 256.
//   * w storage 256 floats/thread: wa(row i) pinned "+v" (arch VGPR),
//     wb(row i+128) pinned "+a" (AGPR; unified file, 1 wave/SIMD = 512
//     regs => no spill; launch_bounds(256,1) removes R11's 128-reg cap).
//     gfx950 VALU can source AGPRs directly (unified file), so wb use is
//     free or at worst one accvgpr_read in proven VALU slack.
//   * R11 lesson: NO up-front quad forcing — each quad loads right before
//     its 8 FMAs (compiler pipelines; LDS pipe stays saturated).
//   * R10 lesson: keep literal-offset x2-unrolled STEP (no runtime parity).
// Numerics: each row's FMA sequence, handoff value, tail rounding, tanh
// are IDENTICAL to R9 — only the thread that executes row i+128 changed.
// Schedule (audited, same as R9): phaseA(u): P(col0,u,rp) | Q(col1,u-1,rp^1)
// [u>=1]; phaseB(u): P(col1,u,rp) | Q(col0,u,rp); epilogue Q(col1,TT-1,0).
//
// R13 = R12 resubmitted verbatim: R12's bench was an infra flake
// ("container failed twice", no compile/pytest/profile output). Audited
// for hang risks: no divergent barriers, ~300/512 regs, full hbuf init.

#define TT 2048
#define BB 512
#define HH 256
#define CC 10
#define KH 128   // chain half-length per thread group

__device__ __forceinline__ float ref_tanhf(float x)
{
    const float a1  = 4.89352455891786e-03f;
    const float a3  = 6.37261928875436e-04f;
    const float a5  = 1.48572235717979e-05f;
    const float a7  = 5.12229709037114e-08f;
    const float a9  = -8.60467152213735e-11f;
    const float a11 = 2.00018790482477e-13f;
    const float a13 = -2.76076847742355e-16f;
    const float b0  = 4.89352518554385e-03f;
    const float b2  = 2.26843463243900e-03f;
    const float b4  = 1.18534705686654e-04f;
    const float b6  = 1.19825839466702e-06f;

    const float kClamp = 7.99881172180175781f;
    const float xc = fmaxf(fminf(x, kClamp), -kClamp);
    const float x2 = __fmul_rn(xc, xc);
    float p = fmaf(x2, a13, a11);
    p = fmaf(x2, p, a9);
    p = fmaf(x2, p, a7);
    p = fmaf(x2, p, a5);
    p = fmaf(x2, p, a3);
    p = fmaf(x2, p, a1);
    p = __fmul_rn(xc, p);
    float q = fmaf(x2, b6, b4);
    q = fmaf(x2, q, b2);
    q = fmaf(x2, q, b0);
    const float r = __fdiv_rn(p, q);
    return (fabsf(x) < 0.0004f) ? x : r;
}

__global__ __launch_bounds__(256, 1)
void rnn_fwd(const float* __restrict__ x,
             const float* __restrict__ W_hx,
             const float* __restrict__ W_hh,
             const float* __restrict__ W_ph,
             const float* __restrict__ bias_h,
             const float* __restrict__ bias_p,
             float* __restrict__ out)
{
    const int tid   = threadIdx.x;
    const int group = tid >> 7;        // 0 = P (k 0..127), 1 = Q (k 128..255)
    const int i     = tid & 127;       // rows {i, i+128}
    const int b0    = blockIdx.x * 2;  // two batch columns per WG

    __shared__ __align__(16) float  xls[2][TT];       // 16 KB
    __shared__ __align__(16) float  hbuf[2][2][HH];   // [col][parity][row] 4 KB
    __shared__ __align__(16) float2 zpart2[2][128];   // packed (za,zb) 2 KB

    // --- stage: two half-rows of W_hh (rows i and i+128, k-half g) ---
    float wa[KH];   // row i      -> arch VGPRs
    float wb[KH];   // row i+128  -> AGPRs (unified file; 1 wave/SIMD)
    {
        const float* __restrict__ ra = W_hh + (size_t)i * HH + group * KH;
        const float* __restrict__ rb = W_hh + (size_t)(i + 128) * HH + group * KH;
#pragma unroll
        for (int k = 0; k < KH; k += 4) {
            const float4 va = *reinterpret_cast<const float4*>(ra + k);
            wa[k] = va.x; wa[k + 1] = va.y; wa[k + 2] = va.z; wa[k + 3] = va.w;
            const float4 vb = *reinterpret_cast<const float4*>(rb + k);
            wb[k] = vb.x; wb[k + 1] = vb.y; wb[k + 2] = vb.z; wb[k + 3] = vb.w;
        }
#pragma unroll
        for (int k = 0; k < KH; ++k) {
            asm volatile("" : "+v"(wa[k]));   // arch VGPR, block remat
        }
#pragma unroll
        for (int k = 0; k < KH; ++k) {
            asm volatile("" : "+a"(wb[k]));   // AGPR, block remat
        }
    }

    // --- stage: x rows (2*TT contiguous floats) -> LDS, 256 threads ---
    {
        const float4* __restrict__ xsrc =
            reinterpret_cast<const float4*>(x + (size_t)b0 * TT);
        float4* __restrict__ xdst = reinterpret_cast<float4*>(&xls[0][0]);
        xdst[tid]       = xsrc[tid];
        xdst[256 + tid] = xsrc[256 + tid];
        xdst[512 + tid] = xsrc[512 + tid];
        xdst[768 + tid] = xsrc[768 + tid];
    }
    const float whxa = W_hx[i];          // used by Q only
    const float whxb = W_hx[i + 128];
    const float bha  = bias_h[i];
    const float bhb  = bias_h[i + 128];

    // h(-1)=0 at parity 1 (step t reads (t&1)^1, writes t&1)
    hbuf[group][1][i]       = 0.0f;   // group doubles as col index here
    hbuf[group][1][i + 128] = 0.0f;
    __syncthreads();

// One broadcast h-quad feeding BOTH row chains (8 FMAs), ascending k.
#define G8(N, OFF, KK)                                                        \
    {                                                                         \
        const float4 q##N = *reinterpret_cast<const float4*>(h + (OFF));      \
        za = fmaf(wa[(KK)],     q##N.x, za);                                  \
        za = fmaf(wa[(KK) + 1], q##N.y, za);                                  \
        za = fmaf(wa[(KK) + 2], q##N.z, za);                                  \
        za = fmaf(wa[(KK) + 3], q##N.w, za);                                  \
        zb = fmaf(wb[(KK)],     q##N.x, zb);                                  \
        zb = fmaf(wb[(KK) + 1], q##N.y, zb);                                  \
        zb = fmaf(wb[(KK) + 2], q##N.z, zb);                                  \
        zb = fmaf(wb[(KK) + 3], q##N.w, zb);                                  \
    }

// 32 quads covering a 128-float k-half starting at h+HB.
#define GALL(HB)                                                              \
    G8(0,  (HB) + 0,   0)   G8(1,  (HB) + 4,   4)                             \
    G8(2,  (HB) + 8,   8)   G8(3,  (HB) + 12,  12)                            \
    G8(4,  (HB) + 16,  16)  G8(5,  (HB) + 20,  20)                            \
    G8(6,  (HB) + 24,  24)  G8(7,  (HB) + 28,  28)                            \
    G8(8,  (HB) + 32,  32)  G8(9,  (HB) + 36,  36)                            \
    G8(10, (HB) + 40,  40)  G8(11, (HB) + 44,  44)                            \
    G8(12, (HB) + 48,  48)  G8(13, (HB) + 52,  52)                            \
    G8(14, (HB) + 56,  56)  G8(15, (HB) + 60,  60)                            \
    G8(16, (HB) + 64,  64)  G8(17, (HB) + 68,  68)                            \
    G8(18, (HB) + 72,  72)  G8(19, (HB) + 76,  76)                            \
    G8(20, (HB) + 80,  80)  G8(21, (HB) + 84,  84)                            \
    G8(22, (HB) + 88,  88)  G8(23, (HB) + 92,  92)                            \
    G8(24, (HB) + 96,  96)  G8(25, (HB) + 100, 100)                           \
    G8(26, (HB) + 104, 104) G8(27, (HB) + 108, 108)                           \
    G8(28, (HB) + 112, 112) G8(29, (HB) + 116, 116)                           \
    G8(30, (HB) + 120, 120) G8(31, (HB) + 124, 124)

// P half-chains (rows i, i+128): k = 0..127, init 0, store exact partials.
#define PBODY(COL, T, RP)                                                     \
    {                                                                         \
        const float* __restrict__ h = &hbuf[(COL)][(RP)][0];                  \
        float za = 0.0f, zb = 0.0f;                                           \
        GALL(0)                                                               \
        zpart2[(COL)][i] = make_float2(za, zb);                               \
    }

// Q half-chains: resume k = 128..255, then x/bias/tanh, write parity RP^1.
#define QBODY(COL, T, RP)                                                     \
    {                                                                         \
        const float* __restrict__ h = &hbuf[(COL)][(RP)][0];                  \
        const float2 zp = zpart2[(COL)][i];                                   \
        float za = zp.x, zb = zp.y;                                           \
        GALL(KH)                                                              \
        const float xt = xls[(COL)][(T)];                                     \
        za = __fadd_rn(__fadd_rn(__fmul_rn(whxa, xt), za), bha);              \
        zb = __fadd_rn(__fadd_rn(__fmul_rn(whxb, xt), zb), bhb);              \
        hbuf[(COL)][(RP) ^ 1][i]       = ref_tanhf(za);                       \
        hbuf[(COL)][(RP) ^ 1][i + 128] = ref_tanhf(zb);                       \
    }

// One u-iteration with compile-time read-parity RP = (u&1)^1.
#define STEP(U, RP)                                                           \
    {                                                                         \
        if (group == 0) { PBODY(0, (U), (RP)) }                               \
        else if ((U) >= 1) { QBODY(1, (U) - 1, (RP) ^ 1) }                    \
        __syncthreads();                                                      \
        if (group == 0) { PBODY(1, (U), (RP)) }                               \
        else { QBODY(0, (U), (RP)) }                                          \
        __syncthreads();                                                      \
    }

    // u=0 peeled (resolves the u>=1 guard), then pairs with constant parity.
    STEP(0, 1)
    for (int u = 1; u + 1 < TT; u += 2) {
        STEP(u, 0)
        STEP(u + 1, 1)
    }
    STEP(TT - 1, 0)                       // u = 2047 (odd -> rp = 0)
    if (group == 1) { QBODY(1, TT - 1, 0) }   // drain pipeline: col1, last step
    __syncthreads();

#undef STEP
#undef QBODY
#undef PBODY
#undef GALL
#undef G8

    // epilogue: p[b,c] = sum_k h_T[k]*W_ph[c,k] + bias_p[c]
    // last step t = TT-1 wrote parity (TT-1)&1 = 1
    if (tid < 2 * CC) {
        const int col = tid / CC;
        const int c   = tid % CC;
        const float* __restrict__ wp = W_ph + (size_t)c * HH;
        const float* __restrict__ hf = hbuf[col][1];
        float pv = 0.0f;
#pragma unroll 8
        for (int k = 0; k < HH; ++k) {
            pv = fmaf(hf[k], wp[k], pv);
        }
        out[(size_t)(b0 + col) * CC + c] = __fadd_rn(pv, bias_p[c]);
    }
}

extern "C" void kernel_launch(void* const* d_in, const int* in_sizes, int n_in,
                              void* d_out, int out_size, void* d_ws, size_t ws_size,
                              hipStream_t stream) {
    const float* x      = (const float*)d_in[0];
    const float* W_hx   = (const float*)d_in[1];
    const float* W_hh   = (const float*)d_in[2];
    const float* W_ph   = (const float*)d_in[3];
    const float* bias_h = (const float*)d_in[4];
    const float* bias_p = (const float*)d_in[5];
    float* out = (float*)d_out;

    rnn_fwd<<<dim3(BB / 2), dim3(256), 0, stream>>>(x, W_hx, W_hh, W_ph, bias_h, bias_p, out);
}

// Round 5
// 3916.262 us; speedup vs baseline: 3.6851x; 3.6851x over previous
//
#include <hip/hip_runtime.h>
#include <math.h>

// VanillaRNN, bit-exact (R9-lineage). Numerics FROZEN:
//   * z[i] = ascending-k single FMA chain k=0..255, init 0, split P: k=0..127
//     -> exact float LDS handoff (zpart) -> Q: k=128..255.
//   * z = ((W_hx*x_t) + chain) + bias_h, separately rounded, left-assoc
//   * tanh = Eigen/XLA fast-tanh WITH FMA (clamp 7.99881172180175781f)
//
// R14 — hybrid h-transport (R10's idea minus R10's de-unroll confound):
//   * Established: LDS return BW is the wall (512 broadcast b128/u-iter x
//     ~7cyc ~= 3600cyc = measured); >=1000cyc/u-iter VALU slack exists
//     (R8->R9); 256 w/thread spills (R13: WRITE_SIZE 24KB->103MB).
//   * Fix: per 128-chain, alternate 16-element blocks:
//       BC16 = 4x broadcast ds_read_b128        (LDS pipe)
//       RL16 = 16x v_readlane from preload hq   (VALU pipe, register-only)
//     One lane-distinct ds_read_b128 preload/body gives lane l = h[4l..4l+3]
//     => wave holds all 256 h; readlane lane/component indices are literals.
//     LDS instrs/u-iter: 512 -> 272 (~1980cyc); VALU += 1024 RL (in slack).
//     Transport-only change: same floats, same chain order => bit-exact.
//   * Skeleton = R9 verbatim: literal-offset x2-unrolled STEP (R10 lesson),
//     same staging/pins (R11/R13 lesson: no forcing, no 256-float arrays),
//     launch_bounds(512,2), same barriers, same epilogue.
// Schedule (audited, R9): phaseA(u): P(col0,u,rp) | Q(col1,u-1,rp^1) [u>=1];
// phaseB(u): P(col1,u,rp) | Q(col0,u,rp); drain Q(col1,TT-1,0); rp=(u&1)^1.

#define TT 2048
#define BB 512
#define HH 256
#define CC 10
#define KH 128   // chain half-length per thread group

__device__ __forceinline__ float ref_tanhf(float x)
{
    const float a1  = 4.89352455891786e-03f;
    const float a3  = 6.37261928875436e-04f;
    const float a5  = 1.48572235717979e-05f;
    const float a7  = 5.12229709037114e-08f;
    const float a9  = -8.60467152213735e-11f;
    const float a11 = 2.00018790482477e-13f;
    const float a13 = -2.76076847742355e-16f;
    const float b0  = 4.89352518554385e-03f;
    const float b2  = 2.26843463243900e-03f;
    const float b4  = 1.18534705686654e-04f;
    const float b6  = 1.19825839466702e-06f;

    const float kClamp = 7.99881172180175781f;
    const float xc = fmaxf(fminf(x, kClamp), -kClamp);
    const float x2 = __fmul_rn(xc, xc);
    float p = fmaf(x2, a13, a11);
    p = fmaf(x2, p, a9);
    p = fmaf(x2, p, a7);
    p = fmaf(x2, p, a5);
    p = fmaf(x2, p, a3);
    p = fmaf(x2, p, a1);
    p = __fmul_rn(xc, p);
    float q = fmaf(x2, b6, b4);
    q = fmaf(x2, q, b2);
    q = fmaf(x2, q, b0);
    const float r = __fdiv_rn(p, q);
    return (fabsf(x) < 0.0004f) ? x : r;
}

__global__ __launch_bounds__(512, 2)
void rnn_fwd(const float* __restrict__ x,
             const float* __restrict__ W_hx,
             const float* __restrict__ W_hh,
             const float* __restrict__ W_ph,
             const float* __restrict__ bias_h,
             const float* __restrict__ bias_p,
             float* __restrict__ out)
{
    const int tid   = threadIdx.x;
    const int group = tid >> 8;        // 0 = P (k 0..127), 1 = Q (k 128..255)
    const int i     = tid & (HH - 1);  // hidden row
    const int l     = tid & 63;        // lane id (preload layout)
    const int b0    = blockIdx.x * 2;  // two batch columns per WG

    __shared__ __align__(16) float xls[2][TT];        // 16 KB
    __shared__ __align__(16) float hbuf[2][2][HH];    // [col][parity][row] 4 KB
    __shared__ __align__(16) float zpart[2][HH];      // 2 KB

    // --- stage: this thread's half-row of W_hh -> 128 regs (R9 exact) ---
    float w[KH];
    const float* __restrict__ wrow = W_hh + (size_t)i * HH + group * KH;
#pragma unroll
    for (int k = 0; k < KH; k += 4) {
        const float4 v = *reinterpret_cast<const float4*>(wrow + k);
        w[k] = v.x; w[k + 1] = v.y; w[k + 2] = v.z; w[k + 3] = v.w;
    }
#pragma unroll
    for (int k = 0; k < KH; ++k) {
        asm volatile("" : "+v"(w[k]));   // block rematerialization
    }

    // --- stage: x rows (2*TT contiguous floats) -> LDS, 512 threads ---
    {
        const float4* __restrict__ xsrc =
            reinterpret_cast<const float4*>(x + (size_t)b0 * TT);
        float4* __restrict__ xdst = reinterpret_cast<float4*>(&xls[0][0]);
        xdst[tid]       = xsrc[tid];
        xdst[512 + tid] = xsrc[512 + tid];
    }
    const float whx = W_hx[i];     // used by Q only
    const float bh  = bias_h[i];   // used by Q only

    // h(-1)=0 at parity 1 (step t reads (t&1)^1, writes t&1)
    hbuf[group][1][i] = 0.0f;
    __syncthreads();

// readlane of a preloaded h component (uniform -> SGPR operand in the FMA)
#define RLF(V, L) __int_as_float(__builtin_amdgcn_readlane(__float_as_int(V), (L)))

// 4 chain FMAs, h via readlane from preload hq; lane = LB + (KL>>2), literal.
#define RL4(KL, LB)                                                           \
    {                                                                         \
        z = fmaf(w[(KL) + 0], RLF(hq.x, (LB) + ((KL) >> 2)), z);              \
        z = fmaf(w[(KL) + 1], RLF(hq.y, (LB) + ((KL) >> 2)), z);              \
        z = fmaf(w[(KL) + 2], RLF(hq.z, (LB) + ((KL) >> 2)), z);              \
        z = fmaf(w[(KL) + 3], RLF(hq.w, (LB) + ((KL) >> 2)), z);              \
    }
#define RL16(KL, LB) RL4((KL), LB) RL4((KL) + 4, LB) RL4((KL) + 8, LB) RL4((KL) + 12, LB)

// 4 chain FMAs, h via broadcast ds_read_b128 at literal offset HB+KL.
#define BC4(KL, HB)                                                           \
    {                                                                         \
        const float4 h4 = *reinterpret_cast<const float4*>(h + (HB) + (KL));  \
        z = fmaf(w[(KL) + 0], h4.x, z);                                       \
        z = fmaf(w[(KL) + 1], h4.y, z);                                       \
        z = fmaf(w[(KL) + 2], h4.z, z);                                       \
        z = fmaf(w[(KL) + 3], h4.w, z);                                       \
    }
#define BC16(KL, HB) BC4((KL), HB) BC4((KL) + 4, HB) BC4((KL) + 8, HB) BC4((KL) + 12, HB)

// P half-chain: k = 0..127, init 0, store exact partial.
// Preload: lane l holds h[4l..4l+3] (one lane-distinct b128; wave = all h).
// Alternate BC16 (LDS pipe) / RL16 (VALU pipe), ascending k (bit-exact).
#define PBODY(COL, T, RP)                                                     \
    {                                                                         \
        const float* __restrict__ h = &hbuf[(COL)][(RP)][0];                  \
        const float4 hq = reinterpret_cast<const float4*>(h)[l];              \
        float z = 0.0f;                                                       \
        BC16(0, 0)    RL16(16, 0)                                             \
        BC16(32, 0)   RL16(48, 0)                                             \
        BC16(64, 0)   RL16(80, 0)                                             \
        BC16(96, 0)   RL16(112, 0)                                            \
        zpart[(COL)][i] = z;                                                  \
    }

// Q half-chain: resume k = 128..255 (local j = k-128), then x/bias/tanh,
// write parity RP^1. RL lanes offset by 32 (global k = 128 + j).
#define QBODY(COL, T, RP)                                                     \
    {                                                                         \
        const float* __restrict__ h = &hbuf[(COL)][(RP)][0];                  \
        const float4 hq = reinterpret_cast<const float4*>(h)[l];              \
        float z = zpart[(COL)][i];                                            \
        BC16(0, KH)    RL16(16, 32)                                           \
        BC16(32, KH)   RL16(48, 32)                                           \
        BC16(64, KH)   RL16(80, 32)                                           \
        BC16(96, KH)   RL16(112, 32)                                          \
        const float a0 = __fmul_rn(whx, xls[(COL)][(T)]);                     \
        z = __fadd_rn(__fadd_rn(a0, z), bh);                                  \
        hbuf[(COL)][(RP) ^ 1][i] = ref_tanhf(z);                              \
    }

// One u-iteration with compile-time read-parity RP = (u&1)^1.
#define STEP(U, RP)                                                           \
    {                                                                         \
        if (group == 0) { PBODY(0, (U), (RP)) }                               \
        else if ((U) >= 1) { QBODY(1, (U) - 1, (RP) ^ 1) }                    \
        __syncthreads();                                                      \
        if (group == 0) { PBODY(1, (U), (RP)) }                               \
        else { QBODY(0, (U), (RP)) }                                          \
        __syncthreads();                                                      \
    }

    // u=0 peeled (resolves the u>=1 guard), then pairs with constant parity.
    STEP(0, 1)
    for (int u = 1; u + 1 < TT; u += 2) {
        STEP(u, 0)
        STEP(u + 1, 1)
    }
    STEP(TT - 1, 0)                       // u = 2047 (odd -> rp = 0)
    if (group == 1) { QBODY(1, TT - 1, 0) }   // drain pipeline: col1, last step
    __syncthreads();

#undef STEP
#undef QBODY
#undef PBODY
#undef BC16
#undef BC4
#undef RL16
#undef RL4
#undef RLF

    // epilogue: p[b,c] = sum_k h_T[k]*W_ph[c,k] + bias_p[c]
    // last step t = TT-1 wrote parity (TT-1)&1 = 1
    if (tid < 2 * CC) {
        const int col = tid / CC;
        const int c   = tid % CC;
        const float* __restrict__ wp = W_ph + (size_t)c * HH;
        const float* __restrict__ hf = hbuf[col][1];
        float pv = 0.0f;
#pragma unroll 8
        for (int k = 0; k < HH; ++k) {
            pv = fmaf(hf[k], wp[k], pv);
        }
        out[(size_t)(b0 + col) * CC + c] = __fadd_rn(pv, bias_p[c]);
    }
}

extern "C" void kernel_launch(void* const* d_in, const int* in_sizes, int n_in,
                              void* d_out, int out_size, void* d_ws, size_t ws_size,
                              hipStream_t stream) {
    const float* x      = (const float*)d_in[0];
    const float* W_hx   = (const float*)d_in[1];
    const float* W_hh   = (const float*)d_in[2];
    const float* W_ph   = (const float*)d_in[3];
    const float* bias_h = (const float*)d_in[4];
    const float* bias_p = (const float*)d_in[5];
    float* out = (float*)d_out;

    rnn_fwd<<<dim3(BB / 2), dim3(512), 0, stream>>>(x, W_hx, W_hh, W_ph, bias_h, bias_p, out);
}